// Round 5
// baseline (431.398 us; speedup 1.0000x reference)
//
#include <hip/hip_runtime.h>
#include <math.h>

#define NROWS 16384
#define DIN   1024
#define DEMB  256
#define KC    1024
#define ALPHA 0.01f
#define EPSV  1e-5f
#define INV2048 4.8828125e-4f

typedef _Float16 f16;
typedef __attribute__((ext_vector_type(4)))  _Float16 f16x4;
typedef __attribute__((ext_vector_type(8)))  _Float16 f16x8;
typedef __attribute__((ext_vector_type(16))) float    f32x16;
typedef unsigned long long u64;

// ---- workspace layout (float-element offsets, 16-aligned) ----
#define OFF_Z       0          // NROWS*DEMB = 4194304 (fp32 z)
#define OFF_R       4194304    // KC*DIN = 1048576
#define OFF_SQR     5242880    // KC
#define OFF_ZH      5243904    // NROWS*DEMB f16 = 2097152 floats
#define OFF_ZL      7341056    // 2097152
#define OFF_WTH     9438208    // DEMB*DIN f16 = 131072 floats
#define OFF_WTL     9569280    // 131072
#define OFF_CBH     9700352    // KC*DEMB f16 = 131072 floats
#define OFF_CBL     9831424    // 131072
#define OFF_KEYS    9962496    // NROWS u64 = 32768 floats (memset 0xFF)
#define OFF_CODES   9995264    // NROWS ints
#define OFF_LIST    10011648   // NROWS ints (bucketed row ids)
#define OFF_OFFS    10028032   // KC ints (exclusive prefix)
#define OFF_HIST    10029056   // KC ints   (zeroed)
#define OFF_CURSOR  10030080   // KC ints   (zeroed)
#define OFF_LOSS    10031104   // 16        (zeroed)
#define ZERO_LEN    2064       // HIST+CURSOR+LOSS contiguous
#define OFF_COUNTSF 10031120   // KC floats
#define OFF_SIZE    10032144   // KC floats
#define OFF_UPD     10033168   // KC*DEMB = 262144 (plain stores, no zero needed)
// total 10295312 floats ~41.2 MB

// ---- output layout (float-element offsets) ----
#define OUT_X      0           // NROWS*DIN
#define OUT_CODES  16777216    // NROWS
#define OUT_EMB    16793600
#define OUT_COMMIT 16793601
#define OUT_ENT    16793602
#define OUT_EMAV   16793603    // KC*DEMB
#define OUT_EMAS   17055747    // KC
#define OUT_W      17056771    // KC*DEMB

__device__ __forceinline__ void split_f32(float x, f16& h, f16& l) {
    h = (f16)x;
    l = (f16)((x - (float)h) * 2048.0f);
}

// ---------------------------------------------------------------------------
__global__ __launch_bounds__(64) void sqr_kernel(const float* __restrict__ cb,
                                                 float* __restrict__ sqr) {
    int k = blockIdx.x;
    int lane = threadIdx.x;
    float4 v = ((const float4*)cb)[k * 64 + lane];
    float s = v.x * v.x + v.y * v.y + v.z * v.z + v.w * v.w;
    for (int off = 32; off > 0; off >>= 1) s += __shfl_down(s, off, 64);
    if (lane == 0) sqr[k] = s;
}

// ---------------------------------------------------------------------------
// W_send [1024,256] -> WT_hi/WT_lo [256][1024] (transposed, f16 split)
__global__ __launch_bounds__(256) void split_wt_kernel(const float* __restrict__ W,
                                                       f16* __restrict__ wth,
                                                       f16* __restrict__ wtl) {
    int n = blockIdx.x;
    int t = threadIdx.x;
    f16x4 h4, l4;
#pragma unroll
    for (int j = 0; j < 4; ++j) {
        int k = t * 4 + j;
        float x = W[(size_t)k * DEMB + n];
        f16 h, l; split_f32(x, h, l);
        h4[j] = h; l4[j] = l;
    }
    *(f16x4*)&wth[(size_t)n * DIN + t * 4] = h4;
    *(f16x4*)&wtl[(size_t)n * DIN + t * 4] = l4;
}

// ---------------------------------------------------------------------------
__global__ __launch_bounds__(256) void split_cb_kernel(const float* __restrict__ cb,
                                                       f16* __restrict__ cbh,
                                                       f16* __restrict__ cbl) {
    int idx = (blockIdx.x * 256 + threadIdx.x) * 4;
    float4 v = *(const float4*)&cb[idx];
    f16x4 h4, l4;
    f16 h, l;
    split_f32(v.x, h, l); h4[0] = h; l4[0] = l;
    split_f32(v.y, h, l); h4[1] = h; l4[1] = l;
    split_f32(v.z, h, l); h4[2] = h; l4[2] = l;
    split_f32(v.w, h, l); h4[3] = h; l4[3] = l;
    *(f16x4*)&cbh[idx] = h4;
    *(f16x4*)&cbl[idx] = l4;
}

// ---------------------------------------------------------------------------
// z = input @ W_send + b_send via f16x3 MFMA (32x32x16), + z hi/lo split out.
__global__ __launch_bounds__(128) void gemm1_mfma(const float* __restrict__ in,
                                                  const f16* __restrict__ wth,
                                                  const f16* __restrict__ wtl,
                                                  const float* __restrict__ bsend,
                                                  float* __restrict__ z,
                                                  f16* __restrict__ zh,
                                                  f16* __restrict__ zl) {
    __shared__ f16 sAh[64 * 72], sAl[64 * 72];
    __shared__ f16 sBh[128 * 72], sBl[128 * 72];
    const int tid = threadIdx.x;
    const int wave = tid >> 6, lane = tid & 63;
    const int half = lane >> 5, l31 = lane & 31;
    const int rowBase = blockIdx.y * 64;
    const int colBase = blockIdx.x * 128;

    f32x16 accm[2][2] = {};
    f32x16 accx[2][2] = {};

    const int ar = tid >> 1;
    const int ak = (tid & 1) * 32;

    for (int ks = 0; ks < DIN; ks += 64) {
        __syncthreads();
#pragma unroll
        for (int i = 0; i < 8; ++i) {
            float4 v = *(const float4*)&in[(size_t)(rowBase + ar) * DIN + ks + ak + i * 4];
            f16x4 h4, l4; f16 h, l;
            split_f32(v.x, h, l); h4[0] = h; l4[0] = l;
            split_f32(v.y, h, l); h4[1] = h; l4[1] = l;
            split_f32(v.z, h, l); h4[2] = h; l4[2] = l;
            split_f32(v.w, h, l); h4[3] = h; l4[3] = l;
            *(f16x4*)&sAh[ar * 72 + ak + i * 4] = h4;
            *(f16x4*)&sAl[ar * 72 + ak + i * 4] = l4;
        }
#pragma unroll
        for (int i = 0; i < 8; ++i) {
            f16x8 bh = *(const f16x8*)&wth[(size_t)(colBase + tid) * DIN + ks + i * 8];
            f16x8 bl = *(const f16x8*)&wtl[(size_t)(colBase + tid) * DIN + ks + i * 8];
            *(f16x8*)&sBh[tid * 72 + i * 8] = bh;
            *(f16x8*)&sBl[tid * 72 + i * 8] = bl;
        }
        __syncthreads();
#pragma unroll
        for (int t4 = 0; t4 < 4; ++t4) {
            int seg = t4 * 2 + half;
            f16x8 a_h[2], a_l[2], b_h[2], b_l[2];
#pragma unroll
            for (int rt = 0; rt < 2; ++rt) {
                a_h[rt] = *(const f16x8*)&sAh[(rt * 32 + l31) * 72 + seg * 8];
                a_l[rt] = *(const f16x8*)&sAl[(rt * 32 + l31) * 72 + seg * 8];
            }
#pragma unroll
            for (int ct = 0; ct < 2; ++ct) {
                int nl = wave * 64 + ct * 32 + l31;
                b_h[ct] = *(const f16x8*)&sBh[nl * 72 + seg * 8];
                b_l[ct] = *(const f16x8*)&sBl[nl * 72 + seg * 8];
            }
#pragma unroll
            for (int rt = 0; rt < 2; ++rt)
#pragma unroll
                for (int ct = 0; ct < 2; ++ct) {
                    accm[rt][ct] = __builtin_amdgcn_mfma_f32_32x32x16_f16(
                        a_h[rt], b_h[ct], accm[rt][ct], 0, 0, 0);
                    accx[rt][ct] = __builtin_amdgcn_mfma_f32_32x32x16_f16(
                        a_h[rt], b_l[ct], accx[rt][ct], 0, 0, 0);
                    accx[rt][ct] = __builtin_amdgcn_mfma_f32_32x32x16_f16(
                        a_l[rt], b_h[ct], accx[rt][ct], 0, 0, 0);
                }
        }
    }

#pragma unroll
    for (int rt = 0; rt < 2; ++rt)
#pragma unroll
        for (int ct = 0; ct < 2; ++ct) {
            int col = colBase + wave * 64 + ct * 32 + l31;
            float bb = bsend[col];
#pragma unroll
            for (int reg = 0; reg < 16; ++reg) {
                int row = rowBase + rt * 32 + (reg & 3) + 8 * (reg >> 2) + 4 * half;
                float zv = accm[rt][ct][reg] + INV2048 * accx[rt][ct][reg] + bb;
                size_t o = (size_t)row * DEMB + col;
                z[o] = zv;
                f16 h = (f16)zv;
                zh[o] = h;
                zl[o] = (f16)((zv - (float)h) * 2048.0f);
            }
        }
}

// ---------------------------------------------------------------------------
// cov + argmin via f16x3 MFMA; packed atomicMin keys give first-min codes.
__global__ __launch_bounds__(128) void cov_mfma_kernel(const f16* __restrict__ zh,
                                                       const f16* __restrict__ zl,
                                                       const f16* __restrict__ cbh,
                                                       const f16* __restrict__ cbl,
                                                       const float* __restrict__ sqr,
                                                       u64* __restrict__ keys) {
    __shared__ f16 sCh[32 * 264], sCl[32 * 264];
    const int tid = threadIdx.x;
    const int wave = tid >> 6, lane = tid & 63;
    const int half = lane >> 5, l31 = lane & 31;
    const int rowBase = blockIdx.y * 64 + wave * 32;
    const int myRow = rowBase + l31;

    f16x8 a_h[16], a_l[16];
#pragma unroll
    for (int t = 0; t < 16; ++t) {
        size_t o = (size_t)myRow * DEMB + t * 16 + half * 8;
        a_h[t] = *(const f16x8*)&zh[o];
        a_l[t] = *(const f16x8*)&zl[o];
    }

    float runv[16];
    int   runc[16];
#pragma unroll
    for (int r = 0; r < 16; ++r) { runv[r] = 3.4e38f; runc[r] = 0; }

    const int stage_code = tid >> 2;
    const int stage_part = (tid & 3) * 64;

    for (int c = blockIdx.x * 16; c < blockIdx.x * 16 + 16; ++c) {
        __syncthreads();
        size_t gbase = (size_t)(c * 32 + stage_code) * DEMB + stage_part;
#pragma unroll
        for (int i = 0; i < 8; ++i) {
            f16x8 bh = *(const f16x8*)&cbh[gbase + i * 8];
            f16x8 bl = *(const f16x8*)&cbl[gbase + i * 8];
            *(f16x8*)&sCh[stage_code * 264 + stage_part + i * 8] = bh;
            *(f16x8*)&sCl[stage_code * 264 + stage_part + i * 8] = bl;
        }
        __syncthreads();

        f32x16 accm = {};
        f32x16 accx = {};
#pragma unroll
        for (int t = 0; t < 16; ++t) {
            int seg = t * 2 + half;
            f16x8 b_h = *(const f16x8*)&sCh[l31 * 264 + seg * 8];
            f16x8 b_l = *(const f16x8*)&sCl[l31 * 264 + seg * 8];
            accm = __builtin_amdgcn_mfma_f32_32x32x16_f16(a_h[t], b_h, accm, 0, 0, 0);
            accx = __builtin_amdgcn_mfma_f32_32x32x16_f16(a_h[t], b_l, accx, 0, 0, 0);
            accx = __builtin_amdgcn_mfma_f32_32x32x16_f16(a_l[t], b_h, accx, 0, 0, 0);
        }

        int code = c * 32 + l31;
        float sqv = sqr[code];
#pragma unroll
        for (int r = 0; r < 16; ++r) {
            float s = sqv - 2.0f * (accm[r] + INV2048 * accx[r]);
            if (s < runv[r]) { runv[r] = s; runc[r] = code; }
        }
    }

#pragma unroll
    for (int r = 0; r < 16; ++r) {
        float v = runv[r]; int ci = runc[r];
        for (int off = 16; off > 0; off >>= 1) {
            float ov = __shfl_down(v, off, 32);
            int   oc = __shfl_down(ci, off, 32);
            if (ov < v || (ov == v && oc < ci)) { v = ov; ci = oc; }
        }
        if (l31 == 0) {
            int row = rowBase + (r & 3) + 8 * (r >> 2) + 4 * half;
            unsigned ub = __float_as_uint(v);
            ub = (ub & 0x80000000u) ? ~ub : (ub | 0x80000000u);
            u64 key = ((u64)ub << 32) | (unsigned)ci;
            atomicMin(&keys[row], key);
        }
    }
}

// ---------------------------------------------------------------------------
// decode keys -> codes (+float codes out) and build histogram
__global__ __launch_bounds__(256) void decode_kernel(const u64* __restrict__ keys,
                                                     int* __restrict__ codes,
                                                     float* __restrict__ out_codes,
                                                     int* __restrict__ hist) {
    int r = blockIdx.x * 256 + threadIdx.x;
    int c = (int)(keys[r] & 0xFFFFFFFFull);
    codes[r] = c;
    out_codes[r] = (float)c;
    atomicAdd(&hist[c], 1);
}

// ---------------------------------------------------------------------------
// exclusive prefix over hist (1 block of 1024); also counts as float
__global__ __launch_bounds__(1024) void prefix_kernel(const int* __restrict__ hist,
                                                      int* __restrict__ offs,
                                                      float* __restrict__ countsf) {
    __shared__ int s[1024];
    int t = threadIdx.x;
    int v = hist[t];
    s[t] = v;
    countsf[t] = (float)v;
    __syncthreads();
    for (int d = 1; d < 1024; d <<= 1) {
        int x = (t >= d) ? s[t - d] : 0;
        __syncthreads();
        s[t] += x;
        __syncthreads();
    }
    offs[t] = s[t] - v;
}

// ---------------------------------------------------------------------------
__global__ __launch_bounds__(256) void fill_kernel(const int* __restrict__ codes,
                                                   const int* __restrict__ offs,
                                                   int* __restrict__ cursor,
                                                   int* __restrict__ list) {
    int r = blockIdx.x * 256 + threadIdx.x;
    int c = codes[r];
    int pos = offs[c] + atomicAdd(&cursor[c], 1);
    list[pos] = r;
}

// ---------------------------------------------------------------------------
// per-code owned reduction: upd[k] = sum z rows; loss += sum ||z-cb[k]||^2.
// block k = 128 thr (2 waves split the rows), lane owns 4 dims (float4).
__global__ __launch_bounds__(128) void upd_loss_kernel(const float* __restrict__ z,
                                                       const float* __restrict__ cb,
                                                       const int* __restrict__ list,
                                                       const int* __restrict__ offs,
                                                       const int* __restrict__ hist,
                                                       float* __restrict__ upd,
                                                       float* __restrict__ loss) {
    const int k = blockIdx.x;
    const int wave = threadIdx.x >> 6, t = threadIdx.x & 63;
    const int beg = offs[k], cnt = hist[k];
    const int halfc = (cnt + 1) >> 1;
    const int s = beg + wave * halfc;
    const int e = min(beg + cnt, s + halfc);

    float4 cbv = ((const float4*)(cb + (size_t)k * DEMB))[t];
    float ax = 0.f, ay = 0.f, az = 0.f, aw = 0.f, lo = 0.f;
    for (int i = s; i < e; ++i) {
        int r = list[i];
        float4 zv = ((const float4*)(z + (size_t)r * DEMB))[t];
        ax += zv.x; ay += zv.y; az += zv.z; aw += zv.w;
        float dx = zv.x - cbv.x, dy = zv.y - cbv.y;
        float dz = zv.z - cbv.z, dw = zv.w - cbv.w;
        lo += dx * dx + dy * dy + dz * dz + dw * dw;
    }

    __shared__ float sacc[64][4];
    __shared__ float slo[2];
    // wave-reduce lo across 64 lanes
    for (int off = 32; off > 0; off >>= 1) lo += __shfl_down(lo, off, 64);
    if (t == 0) slo[wave] = lo;
    if (wave == 1) {
        sacc[t][0] = ax; sacc[t][1] = ay; sacc[t][2] = az; sacc[t][3] = aw;
    }
    __syncthreads();
    if (wave == 0) {
        float4 o = make_float4(ax + sacc[t][0], ay + sacc[t][1],
                               az + sacc[t][2], aw + sacc[t][3]);
        ((float4*)(upd + (size_t)k * DEMB))[t] = o;
        if (t == 0) atomicAdd(loss, slo[0] + slo[1]);
    }
}

// ---------------------------------------------------------------------------
// 64x64-tile fp32 GEMM (R = codebook @ W_recv)
__global__ __launch_bounds__(256) void gemm64_kernel(const float* __restrict__ A,
                                                     const float* __restrict__ B,
                                                     float* __restrict__ C,
                                                     int M, int Kd, int Nc) {
    __shared__ float As[16][68];
    __shared__ float Bs[16][64];
    const int tid = threadIdx.x;
    const int tx = tid & 15, ty = tid >> 4;
    const int rowBase = blockIdx.y * 64;
    const int colBase = blockIdx.x * 64;

    float acc[4][4];
#pragma unroll
    for (int i = 0; i < 4; ++i)
#pragma unroll
        for (int j = 0; j < 4; ++j) acc[i][j] = 0.f;

    const int a_row = tid >> 2;
    const int a_c4  = (tid & 3) * 4;
    const int b_r   = tid >> 4;
    const int b_c4  = (tid & 15) * 4;

    for (int kk = 0; kk < Kd; kk += 16) {
        float4 av = *(const float4*)&A[(size_t)(rowBase + a_row) * Kd + kk + a_c4];
        float4 bv = *(const float4*)&B[(size_t)(kk + b_r) * Nc + colBase + b_c4];
        __syncthreads();
        As[a_c4 + 0][a_row] = av.x;  As[a_c4 + 1][a_row] = av.y;
        As[a_c4 + 2][a_row] = av.z;  As[a_c4 + 3][a_row] = av.w;
        *(float4*)&Bs[b_r][b_c4] = bv;
        __syncthreads();
#pragma unroll
        for (int d = 0; d < 16; ++d) {
            float4 a01 = *(const float4*)&As[d][ty * 4];
            float4 b01 = *(const float4*)&Bs[d][tx * 4];
            float a[4] = {a01.x, a01.y, a01.z, a01.w};
            float b[4] = {b01.x, b01.y, b01.z, b01.w};
#pragma unroll
            for (int i = 0; i < 4; ++i)
#pragma unroll
                for (int j = 0; j < 4; ++j) acc[i][j] += a[i] * b[j];
        }
    }

#pragma unroll
    for (int i = 0; i < 4; ++i) {
        int r = rowBase + ty * 4 + i;
        *(float4*)&C[(size_t)r * Nc + colBase + tx * 4] =
            make_float4(acc[i][0], acc[i][1], acc[i][2], acc[i][3]);
    }
}

// ---------------------------------------------------------------------------
__global__ __launch_bounds__(256) void recv_kernel(const float* __restrict__ R,
                                                   const float* __restrict__ brecv,
                                                   const int* __restrict__ codes,
                                                   float* __restrict__ out) {
    const int n = blockIdx.x;
    const int t = threadIdx.x;
    const int code = codes[n];
    float4 r = ((const float4*)(R + (size_t)code * DIN))[t];
    float4 b = ((const float4*)brecv)[t];
    ((float4*)(out + (size_t)n * DIN))[t] =
        make_float4(r.x + b.x, r.y + b.y, r.z + b.z, r.w + b.w);
}

// ---------------------------------------------------------------------------
__global__ __launch_bounds__(1024) void ema_small_kernel(const float* __restrict__ ema_size,
                                                         const float* __restrict__ counts,
                                                         const float* __restrict__ loss,
                                                         float* __restrict__ size_ws,
                                                         float* __restrict__ out) {
    __shared__ float rn[1024];
    __shared__ float re[1024];
    const int k = threadIdx.x;
    float c  = counts[k];
    float es = ema_size[k];
    float esn = es + ALPHA * (c - es);
    out[OUT_EMAS + k] = esn;
    float p = c * (1.0f / (float)NROWS);
    rn[k] = esn;
    re[k] = (p > 0.f) ? p * logf(p) : 0.f;
    __syncthreads();
    for (int s = 512; s > 0; s >>= 1) {
        if (k < s) { rn[k] += rn[k + s]; re[k] += re[k + s]; }
        __syncthreads();
    }
    float n = rn[0];
    float coef = n / (n + (float)KC * EPSV);
    size_ws[k] = coef * (esn + EPSV);
    if (k == 0) {
        out[OUT_ENT] = -re[0] / logf(2.0f);
        float l = loss[0];
        out[OUT_EMB] = l;
        out[OUT_COMMIT] = l;
    }
}

// ---------------------------------------------------------------------------
__global__ __launch_bounds__(256) void emav_kernel(const float* __restrict__ ema_vecs,
                                                   const float* __restrict__ upd,
                                                   const float* __restrict__ size_ws,
                                                   float* __restrict__ out) {
    int idx = blockIdx.x * 256 + threadIdx.x;
    float ev = ema_vecs[idx], uv = upd[idx];
    float evn = ev + ALPHA * (uv - ev);
    out[OUT_EMAV + idx] = evn;
    out[OUT_W + idx] = evn / size_ws[idx >> 8];
}

// ---------------------------------------------------------------------------
extern "C" void kernel_launch(void* const* d_in, const int* in_sizes, int n_in,
                              void* d_out, int out_size, void* d_ws, size_t ws_size,
                              hipStream_t stream) {
    const float* input    = (const float*)d_in[0];
    const float* W_send   = (const float*)d_in[1];
    const float* b_send   = (const float*)d_in[2];
    const float* W_recv   = (const float*)d_in[3];
    const float* b_recv   = (const float*)d_in[4];
    const float* codebook = (const float*)d_in[5];
    const float* ema_vecs = (const float*)d_in[6];
    const float* ema_size = (const float*)d_in[7];
    float* out = (float*)d_out;
    float* ws  = (float*)d_ws;
    int*   wsi = (int*)d_ws;

    f16* wth = (f16*)(ws + OFF_WTH);
    f16* wtl = (f16*)(ws + OFF_WTL);
    f16* cbh = (f16*)(ws + OFF_CBH);
    f16* cbl = (f16*)(ws + OFF_CBL);
    f16* zh  = (f16*)(ws + OFF_ZH);
    f16* zl  = (f16*)(ws + OFF_ZL);
    u64* keys = (u64*)(ws + OFF_KEYS);

    // zero hist+cursor+loss; keys to all-ones
    (void)hipMemsetAsync(ws + OFF_HIST, 0, (size_t)ZERO_LEN * sizeof(float), stream);
    (void)hipMemsetAsync(ws + OFF_KEYS, 0xFF, (size_t)NROWS * sizeof(u64), stream);

    sqr_kernel<<<KC, 64, 0, stream>>>(codebook, ws + OFF_SQR);
    split_wt_kernel<<<DEMB, 256, 0, stream>>>(W_send, wth, wtl);
    split_cb_kernel<<<256, 256, 0, stream>>>(codebook, cbh, cbl);

    // R = codebook @ W_recv (fp32)
    gemm64_kernel<<<dim3(DIN / 64, KC / 64), 256, 0, stream>>>(
        codebook, W_recv, ws + OFF_R, KC, DEMB, DIN);

    // z = input @ W_send + b_send (f16x3 MFMA) + fused hi/lo split
    gemm1_mfma<<<dim3(DEMB / 128, NROWS / 64), 128, 0, stream>>>(
        input, wth, wtl, b_send, ws + OFF_Z, zh, zl);

    // cov + fused argmin
    cov_mfma_kernel<<<dim3(2, NROWS / 64), 128, 0, stream>>>(
        zh, zl, cbh, cbl, ws + OFF_SQR, keys);

    decode_kernel<<<NROWS / 256, 256, 0, stream>>>(
        keys, wsi + OFF_CODES, out + OUT_CODES, wsi + OFF_HIST);

    prefix_kernel<<<1, 1024, 0, stream>>>(
        wsi + OFF_HIST, wsi + OFF_OFFS, ws + OFF_COUNTSF);

    fill_kernel<<<NROWS / 256, 256, 0, stream>>>(
        wsi + OFF_CODES, wsi + OFF_OFFS, wsi + OFF_CURSOR, wsi + OFF_LIST);

    upd_loss_kernel<<<KC, 128, 0, stream>>>(
        ws + OFF_Z, codebook, wsi + OFF_LIST, wsi + OFF_OFFS, wsi + OFF_HIST,
        ws + OFF_UPD, ws + OFF_LOSS);

    recv_kernel<<<NROWS, 256, 0, stream>>>(
        ws + OFF_R, b_recv, wsi + OFF_CODES, out + OUT_X);

    ema_small_kernel<<<1, 1024, 0, stream>>>(
        ema_size, ws + OFF_COUNTSF, ws + OFF_LOSS, ws + OFF_SIZE, out);

    emav_kernel<<<KC, 256, 0, stream>>>(
        ema_vecs, ws + OFF_UPD, ws + OFF_SIZE, out);
}

// Round 6
// 316.988 us; speedup vs baseline: 1.3609x; 1.3609x over previous
//
#include <hip/hip_runtime.h>
#include <math.h>

#define NROWS 16384
#define DIN   1024
#define DEMB  256
#define KC    1024
#define ALPHA 0.01f
#define EPSV  1e-5f
#define INV2048 4.8828125e-4f
#define CHUNK 32

typedef _Float16 f16;
typedef __attribute__((ext_vector_type(4)))  _Float16 f16x4;
typedef __attribute__((ext_vector_type(8)))  _Float16 f16x8;
typedef __attribute__((ext_vector_type(16))) float    f32x16;
typedef unsigned long long u64;

// ---- workspace layout (float-element offsets, 16-aligned) ----
#define OFF_Z       0          // NROWS*DEMB = 4194304 (fp32 z)
#define OFF_R       4194304    // KC*DIN = 1048576
#define OFF_SQR     5242880    // KC
#define OFF_ZH      5243904    // NROWS*DEMB f16 = 2097152 floats
#define OFF_ZL      7341056    // 2097152
#define OFF_WTH     9438208    // DEMB*DIN f16 = 131072 floats
#define OFF_WTL     9569280    // 131072
#define OFF_CBH     9700352    // KC*DEMB f16 = 131072 floats
#define OFF_CBL     9831424    // 131072
#define OFF_KEYS    9962496    // NROWS u64 = 32768 floats (memset 0xFF)
#define OFF_CODES   9995264    // NROWS ints
#define OFF_LIST    10011648   // NROWS ints (bucketed row ids)
#define OFF_OFFS    10028032   // KC ints (exclusive prefix)
#define OFF_UPD     10029056   // KC*DEMB = 262144 (zeroed: atomic target)
#define OFF_HIST    10291200   // KC ints   (zeroed)
#define OFF_CURSOR  10292224   // KC ints   (zeroed)
#define OFF_LOSS    10293248   // 16        (zeroed)
#define ZERO_LEN    264208     // UPD+HIST+CURSOR+LOSS contiguous
#define OFF_COUNTSF 10293264   // KC floats
#define OFF_SIZE    10294288   // KC floats
// total 10295312 floats ~41.2 MB

// ---- output layout (float-element offsets) ----
#define OUT_X      0           // NROWS*DIN
#define OUT_CODES  16777216    // NROWS
#define OUT_EMB    16793600
#define OUT_COMMIT 16793601
#define OUT_ENT    16793602
#define OUT_EMAV   16793603    // KC*DEMB
#define OUT_EMAS   17055747    // KC
#define OUT_W      17056771    // KC*DEMB

__device__ __forceinline__ void split_f32(float x, f16& h, f16& l) {
    h = (f16)x;
    l = (f16)((x - (float)h) * 2048.0f);
}

// ---------------------------------------------------------------------------
__global__ __launch_bounds__(64) void sqr_kernel(const float* __restrict__ cb,
                                                 float* __restrict__ sqr) {
    int k = blockIdx.x;
    int lane = threadIdx.x;
    float4 v = ((const float4*)cb)[k * 64 + lane];
    float s = v.x * v.x + v.y * v.y + v.z * v.z + v.w * v.w;
    for (int off = 32; off > 0; off >>= 1) s += __shfl_down(s, off, 64);
    if (lane == 0) sqr[k] = s;
}

// ---------------------------------------------------------------------------
// W_send [1024,256] -> WT_hi/WT_lo [256][1024] (transposed, f16 split)
__global__ __launch_bounds__(256) void split_wt_kernel(const float* __restrict__ W,
                                                       f16* __restrict__ wth,
                                                       f16* __restrict__ wtl) {
    int n = blockIdx.x;
    int t = threadIdx.x;
    f16x4 h4, l4;
#pragma unroll
    for (int j = 0; j < 4; ++j) {
        int k = t * 4 + j;
        float x = W[(size_t)k * DEMB + n];
        f16 h, l; split_f32(x, h, l);
        h4[j] = h; l4[j] = l;
    }
    *(f16x4*)&wth[(size_t)n * DIN + t * 4] = h4;
    *(f16x4*)&wtl[(size_t)n * DIN + t * 4] = l4;
}

// ---------------------------------------------------------------------------
__global__ __launch_bounds__(256) void split_cb_kernel(const float* __restrict__ cb,
                                                       f16* __restrict__ cbh,
                                                       f16* __restrict__ cbl) {
    int idx = (blockIdx.x * 256 + threadIdx.x) * 4;
    float4 v = *(const float4*)&cb[idx];
    f16x4 h4, l4;
    f16 h, l;
    split_f32(v.x, h, l); h4[0] = h; l4[0] = l;
    split_f32(v.y, h, l); h4[1] = h; l4[1] = l;
    split_f32(v.z, h, l); h4[2] = h; l4[2] = l;
    split_f32(v.w, h, l); h4[3] = h; l4[3] = l;
    *(f16x4*)&cbh[idx] = h4;
    *(f16x4*)&cbl[idx] = l4;
}

// ---------------------------------------------------------------------------
// z = input @ W_send + b_send via f16x3 MFMA (32x32x16), + z hi/lo split out.
__global__ __launch_bounds__(128) void gemm1_mfma(const float* __restrict__ in,
                                                  const f16* __restrict__ wth,
                                                  const f16* __restrict__ wtl,
                                                  const float* __restrict__ bsend,
                                                  float* __restrict__ z,
                                                  f16* __restrict__ zh,
                                                  f16* __restrict__ zl) {
    __shared__ f16 sAh[64 * 72], sAl[64 * 72];
    __shared__ f16 sBh[128 * 72], sBl[128 * 72];
    const int tid = threadIdx.x;
    const int wave = tid >> 6, lane = tid & 63;
    const int half = lane >> 5, l31 = lane & 31;
    const int rowBase = blockIdx.y * 64;
    const int colBase = blockIdx.x * 128;

    f32x16 accm[2][2] = {};
    f32x16 accx[2][2] = {};

    const int ar = tid >> 1;
    const int ak = (tid & 1) * 32;

    for (int ks = 0; ks < DIN; ks += 64) {
        __syncthreads();
#pragma unroll
        for (int i = 0; i < 8; ++i) {
            float4 v = *(const float4*)&in[(size_t)(rowBase + ar) * DIN + ks + ak + i * 4];
            f16x4 h4, l4; f16 h, l;
            split_f32(v.x, h, l); h4[0] = h; l4[0] = l;
            split_f32(v.y, h, l); h4[1] = h; l4[1] = l;
            split_f32(v.z, h, l); h4[2] = h; l4[2] = l;
            split_f32(v.w, h, l); h4[3] = h; l4[3] = l;
            *(f16x4*)&sAh[ar * 72 + ak + i * 4] = h4;
            *(f16x4*)&sAl[ar * 72 + ak + i * 4] = l4;
        }
#pragma unroll
        for (int i = 0; i < 8; ++i) {
            f16x8 bh = *(const f16x8*)&wth[(size_t)(colBase + tid) * DIN + ks + i * 8];
            f16x8 bl = *(const f16x8*)&wtl[(size_t)(colBase + tid) * DIN + ks + i * 8];
            *(f16x8*)&sBh[tid * 72 + i * 8] = bh;
            *(f16x8*)&sBl[tid * 72 + i * 8] = bl;
        }
        __syncthreads();
#pragma unroll
        for (int t4 = 0; t4 < 4; ++t4) {
            int seg = t4 * 2 + half;
            f16x8 a_h[2], a_l[2], b_h[2], b_l[2];
#pragma unroll
            for (int rt = 0; rt < 2; ++rt) {
                a_h[rt] = *(const f16x8*)&sAh[(rt * 32 + l31) * 72 + seg * 8];
                a_l[rt] = *(const f16x8*)&sAl[(rt * 32 + l31) * 72 + seg * 8];
            }
#pragma unroll
            for (int ct = 0; ct < 2; ++ct) {
                int nl = wave * 64 + ct * 32 + l31;
                b_h[ct] = *(const f16x8*)&sBh[nl * 72 + seg * 8];
                b_l[ct] = *(const f16x8*)&sBl[nl * 72 + seg * 8];
            }
#pragma unroll
            for (int rt = 0; rt < 2; ++rt)
#pragma unroll
                for (int ct = 0; ct < 2; ++ct) {
                    accm[rt][ct] = __builtin_amdgcn_mfma_f32_32x32x16_f16(
                        a_h[rt], b_h[ct], accm[rt][ct], 0, 0, 0);
                    accx[rt][ct] = __builtin_amdgcn_mfma_f32_32x32x16_f16(
                        a_h[rt], b_l[ct], accx[rt][ct], 0, 0, 0);
                    accx[rt][ct] = __builtin_amdgcn_mfma_f32_32x32x16_f16(
                        a_l[rt], b_h[ct], accx[rt][ct], 0, 0, 0);
                }
        }
    }

#pragma unroll
    for (int rt = 0; rt < 2; ++rt)
#pragma unroll
        for (int ct = 0; ct < 2; ++ct) {
            int col = colBase + wave * 64 + ct * 32 + l31;
            float bb = bsend[col];
#pragma unroll
            for (int reg = 0; reg < 16; ++reg) {
                int row = rowBase + rt * 32 + (reg & 3) + 8 * (reg >> 2) + 4 * half;
                float zv = accm[rt][ct][reg] + INV2048 * accx[rt][ct][reg] + bb;
                size_t o = (size_t)row * DEMB + col;
                z[o] = zv;
                f16 h = (f16)zv;
                zh[o] = h;
                zl[o] = (f16)((zv - (float)h) * 2048.0f);
            }
        }
}

// ---------------------------------------------------------------------------
// cov + argmin via f16x3 MFMA; packed atomicMin keys give first-min codes.
__global__ __launch_bounds__(128) void cov_mfma_kernel(const f16* __restrict__ zh,
                                                       const f16* __restrict__ zl,
                                                       const f16* __restrict__ cbh,
                                                       const f16* __restrict__ cbl,
                                                       const float* __restrict__ sqr,
                                                       u64* __restrict__ keys) {
    __shared__ f16 sCh[32 * 264], sCl[32 * 264];
    const int tid = threadIdx.x;
    const int wave = tid >> 6, lane = tid & 63;
    const int half = lane >> 5, l31 = lane & 31;
    const int rowBase = blockIdx.y * 64 + wave * 32;
    const int myRow = rowBase + l31;

    f16x8 a_h[16], a_l[16];
#pragma unroll
    for (int t = 0; t < 16; ++t) {
        size_t o = (size_t)myRow * DEMB + t * 16 + half * 8;
        a_h[t] = *(const f16x8*)&zh[o];
        a_l[t] = *(const f16x8*)&zl[o];
    }

    float runv[16];
    int   runc[16];
#pragma unroll
    for (int r = 0; r < 16; ++r) { runv[r] = 3.4e38f; runc[r] = 0; }

    const int stage_code = tid >> 2;
    const int stage_part = (tid & 3) * 64;

    for (int c = blockIdx.x * 16; c < blockIdx.x * 16 + 16; ++c) {
        __syncthreads();
        size_t gbase = (size_t)(c * 32 + stage_code) * DEMB + stage_part;
#pragma unroll
        for (int i = 0; i < 8; ++i) {
            f16x8 bh = *(const f16x8*)&cbh[gbase + i * 8];
            f16x8 bl = *(const f16x8*)&cbl[gbase + i * 8];
            *(f16x8*)&sCh[stage_code * 264 + stage_part + i * 8] = bh;
            *(f16x8*)&sCl[stage_code * 264 + stage_part + i * 8] = bl;
        }
        __syncthreads();

        f32x16 accm = {};
        f32x16 accx = {};
#pragma unroll
        for (int t = 0; t < 16; ++t) {
            int seg = t * 2 + half;
            f16x8 b_h = *(const f16x8*)&sCh[l31 * 264 + seg * 8];
            f16x8 b_l = *(const f16x8*)&sCl[l31 * 264 + seg * 8];
            accm = __builtin_amdgcn_mfma_f32_32x32x16_f16(a_h[t], b_h, accm, 0, 0, 0);
            accx = __builtin_amdgcn_mfma_f32_32x32x16_f16(a_h[t], b_l, accx, 0, 0, 0);
            accx = __builtin_amdgcn_mfma_f32_32x32x16_f16(a_l[t], b_h, accx, 0, 0, 0);
        }

        int code = c * 32 + l31;
        float sqv = sqr[code];
#pragma unroll
        for (int r = 0; r < 16; ++r) {
            float s = sqv - 2.0f * (accm[r] + INV2048 * accx[r]);
            if (s < runv[r]) { runv[r] = s; runc[r] = code; }
        }
    }

#pragma unroll
    for (int r = 0; r < 16; ++r) {
        float v = runv[r]; int ci = runc[r];
        for (int off = 16; off > 0; off >>= 1) {
            float ov = __shfl_down(v, off, 32);
            int   oc = __shfl_down(ci, off, 32);
            if (ov < v || (ov == v && oc < ci)) { v = ov; ci = oc; }
        }
        if (l31 == 0) {
            int row = rowBase + (r & 3) + 8 * (r >> 2) + 4 * half;
            unsigned ub = __float_as_uint(v);
            ub = (ub & 0x80000000u) ? ~ub : (ub | 0x80000000u);
            u64 key = ((u64)ub << 32) | (unsigned)ci;
            atomicMin(&keys[row], key);
        }
    }
}

// ---------------------------------------------------------------------------
// decode keys -> codes (+float codes out) and build histogram
__global__ __launch_bounds__(256) void decode_kernel(const u64* __restrict__ keys,
                                                     int* __restrict__ codes,
                                                     float* __restrict__ out_codes,
                                                     int* __restrict__ hist) {
    int r = blockIdx.x * 256 + threadIdx.x;
    int c = (int)(keys[r] & 0xFFFFFFFFull);
    codes[r] = c;
    out_codes[r] = (float)c;
    atomicAdd(&hist[c], 1);
}

// ---------------------------------------------------------------------------
// exclusive prefix over hist (1 block of 1024); also counts as float
__global__ __launch_bounds__(1024) void prefix_kernel(const int* __restrict__ hist,
                                                      int* __restrict__ offs,
                                                      float* __restrict__ countsf) {
    __shared__ int s[1024];
    int t = threadIdx.x;
    int v = hist[t];
    s[t] = v;
    countsf[t] = (float)v;
    __syncthreads();
    for (int d = 1; d < 1024; d <<= 1) {
        int x = (t >= d) ? s[t - d] : 0;
        __syncthreads();
        s[t] += x;
        __syncthreads();
    }
    offs[t] = s[t] - v;
}

// ---------------------------------------------------------------------------
__global__ __launch_bounds__(256) void fill_kernel(const int* __restrict__ codes,
                                                   const int* __restrict__ offs,
                                                   int* __restrict__ cursor,
                                                   int* __restrict__ list) {
    int r = blockIdx.x * 256 + threadIdx.x;
    int c = codes[r];
    int pos = offs[c] + atomicAdd(&cursor[c], 1);
    list[pos] = r;
}

// ---------------------------------------------------------------------------
// balanced segment-sum over the sorted list: 32 list entries per block,
// 256 thr = 1 dim each. Register partial per run; atomicAdd flush at run
// boundaries (wave-uniform). Also accumulates commitment loss.
__global__ __launch_bounds__(256) void upd_loss_kernel(const float* __restrict__ z,
                                                       const float* __restrict__ cb,
                                                       const int* __restrict__ list,
                                                       const int* __restrict__ codes,
                                                       float* __restrict__ upd,
                                                       float* __restrict__ loss) {
    __shared__ int srow[CHUNK];
    __shared__ int scode[CHUNK];
    const int tid = threadIdx.x;
    const int base = blockIdx.x * CHUNK;
    if (tid < CHUNK) {
        int r = list[base + tid];
        srow[tid] = r;
        scode[tid] = codes[r];
    }
    __syncthreads();

    int cur = scode[0];
    float cbv = cb[(size_t)cur * DEMB + tid];
    float acc = 0.f, lacc = 0.f;
    float zv = z[(size_t)srow[0] * DEMB + tid];
#pragma unroll 4
    for (int i = 0; i < CHUNK; ++i) {
        float znext = (i + 1 < CHUNK) ? z[(size_t)srow[i + 1] * DEMB + tid] : 0.f;
        int c = scode[i];
        if (c != cur) {                         // wave-uniform branch
            atomicAdd(&upd[(size_t)cur * DEMB + tid], acc);
            acc = 0.f;
            cur = c;
            cbv = cb[(size_t)cur * DEMB + tid];
        }
        acc += zv;
        float d = zv - cbv;
        lacc += d * d;
        zv = znext;
    }
    atomicAdd(&upd[(size_t)cur * DEMB + tid], acc);

    __shared__ float red[256];
    red[tid] = lacc;
    __syncthreads();
    for (int s = 128; s > 0; s >>= 1) {
        if (tid < s) red[tid] += red[tid + s];
        __syncthreads();
    }
    if (tid == 0) atomicAdd(loss, red[0]);
}

// ---------------------------------------------------------------------------
// 64x64-tile fp32 GEMM (R = codebook @ W_recv)
__global__ __launch_bounds__(256) void gemm64_kernel(const float* __restrict__ A,
                                                     const float* __restrict__ B,
                                                     float* __restrict__ C,
                                                     int M, int Kd, int Nc) {
    __shared__ float As[16][68];
    __shared__ float Bs[16][64];
    const int tid = threadIdx.x;
    const int tx = tid & 15, ty = tid >> 4;
    const int rowBase = blockIdx.y * 64;
    const int colBase = blockIdx.x * 64;

    float acc[4][4];
#pragma unroll
    for (int i = 0; i < 4; ++i)
#pragma unroll
        for (int j = 0; j < 4; ++j) acc[i][j] = 0.f;

    const int a_row = tid >> 2;
    const int a_c4  = (tid & 3) * 4;
    const int b_r   = tid >> 4;
    const int b_c4  = (tid & 15) * 4;

    for (int kk = 0; kk < Kd; kk += 16) {
        float4 av = *(const float4*)&A[(size_t)(rowBase + a_row) * Kd + kk + a_c4];
        float4 bv = *(const float4*)&B[(size_t)(kk + b_r) * Nc + colBase + b_c4];
        __syncthreads();
        As[a_c4 + 0][a_row] = av.x;  As[a_c4 + 1][a_row] = av.y;
        As[a_c4 + 2][a_row] = av.z;  As[a_c4 + 3][a_row] = av.w;
        *(float4*)&Bs[b_r][b_c4] = bv;
        __syncthreads();
#pragma unroll
        for (int d = 0; d < 16; ++d) {
            float4 a01 = *(const float4*)&As[d][ty * 4];
            float4 b01 = *(const float4*)&Bs[d][tx * 4];
            float a[4] = {a01.x, a01.y, a01.z, a01.w};
            float b[4] = {b01.x, b01.y, b01.z, b01.w};
#pragma unroll
            for (int i = 0; i < 4; ++i)
#pragma unroll
                for (int j = 0; j < 4; ++j) acc[i][j] += a[i] * b[j];
        }
    }

#pragma unroll
    for (int i = 0; i < 4; ++i) {
        int r = rowBase + ty * 4 + i;
        *(float4*)&C[(size_t)r * Nc + colBase + tx * 4] =
            make_float4(acc[i][0], acc[i][1], acc[i][2], acc[i][3]);
    }
}

// ---------------------------------------------------------------------------
__global__ __launch_bounds__(256) void recv_kernel(const float* __restrict__ R,
                                                   const float* __restrict__ brecv,
                                                   const int* __restrict__ codes,
                                                   float* __restrict__ out) {
    const int n = blockIdx.x;
    const int t = threadIdx.x;
    const int code = codes[n];
    float4 r = ((const float4*)(R + (size_t)code * DIN))[t];
    float4 b = ((const float4*)brecv)[t];
    ((float4*)(out + (size_t)n * DIN))[t] =
        make_float4(r.x + b.x, r.y + b.y, r.z + b.z, r.w + b.w);
}

// ---------------------------------------------------------------------------
__global__ __launch_bounds__(1024) void ema_small_kernel(const float* __restrict__ ema_size,
                                                         const float* __restrict__ counts,
                                                         const float* __restrict__ loss,
                                                         float* __restrict__ size_ws,
                                                         float* __restrict__ out) {
    __shared__ float rn[1024];
    __shared__ float re[1024];
    const int k = threadIdx.x;
    float c  = counts[k];
    float es = ema_size[k];
    float esn = es + ALPHA * (c - es);
    out[OUT_EMAS + k] = esn;
    float p = c * (1.0f / (float)NROWS);
    rn[k] = esn;
    re[k] = (p > 0.f) ? p * logf(p) : 0.f;
    __syncthreads();
    for (int s = 512; s > 0; s >>= 1) {
        if (k < s) { rn[k] += rn[k + s]; re[k] += re[k + s]; }
        __syncthreads();
    }
    float n = rn[0];
    float coef = n / (n + (float)KC * EPSV);
    size_ws[k] = coef * (esn + EPSV);
    if (k == 0) {
        out[OUT_ENT] = -re[0] / logf(2.0f);
        float l = loss[0];
        out[OUT_EMB] = l;
        out[OUT_COMMIT] = l;
    }
}

// ---------------------------------------------------------------------------
__global__ __launch_bounds__(256) void emav_kernel(const float* __restrict__ ema_vecs,
                                                   const float* __restrict__ upd,
                                                   const float* __restrict__ size_ws,
                                                   float* __restrict__ out) {
    int idx = blockIdx.x * 256 + threadIdx.x;
    float ev = ema_vecs[idx], uv = upd[idx];
    float evn = ev + ALPHA * (uv - ev);
    out[OUT_EMAV + idx] = evn;
    out[OUT_W + idx] = evn / size_ws[idx >> 8];
}

// ---------------------------------------------------------------------------
extern "C" void kernel_launch(void* const* d_in, const int* in_sizes, int n_in,
                              void* d_out, int out_size, void* d_ws, size_t ws_size,
                              hipStream_t stream) {
    const float* input    = (const float*)d_in[0];
    const float* W_send   = (const float*)d_in[1];
    const float* b_send   = (const float*)d_in[2];
    const float* W_recv   = (const float*)d_in[3];
    const float* b_recv   = (const float*)d_in[4];
    const float* codebook = (const float*)d_in[5];
    const float* ema_vecs = (const float*)d_in[6];
    const float* ema_size = (const float*)d_in[7];
    float* out = (float*)d_out;
    float* ws  = (float*)d_ws;
    int*   wsi = (int*)d_ws;

    f16* wth = (f16*)(ws + OFF_WTH);
    f16* wtl = (f16*)(ws + OFF_WTL);
    f16* cbh = (f16*)(ws + OFF_CBH);
    f16* cbl = (f16*)(ws + OFF_CBL);
    f16* zh  = (f16*)(ws + OFF_ZH);
    f16* zl  = (f16*)(ws + OFF_ZL);
    u64* keys = (u64*)(ws + OFF_KEYS);

    // zero upd+hist+cursor+loss; keys to all-ones
    (void)hipMemsetAsync(ws + OFF_UPD, 0, (size_t)ZERO_LEN * sizeof(float), stream);
    (void)hipMemsetAsync(ws + OFF_KEYS, 0xFF, (size_t)NROWS * sizeof(u64), stream);

    sqr_kernel<<<KC, 64, 0, stream>>>(codebook, ws + OFF_SQR);
    split_wt_kernel<<<DEMB, 256, 0, stream>>>(W_send, wth, wtl);
    split_cb_kernel<<<256, 256, 0, stream>>>(codebook, cbh, cbl);

    // R = codebook @ W_recv (fp32)
    gemm64_kernel<<<dim3(DIN / 64, KC / 64), 256, 0, stream>>>(
        codebook, W_recv, ws + OFF_R, KC, DEMB, DIN);

    // z = input @ W_send + b_send (f16x3 MFMA) + fused hi/lo split
    gemm1_mfma<<<dim3(DEMB / 128, NROWS / 64), 128, 0, stream>>>(
        input, wth, wtl, b_send, ws + OFF_Z, zh, zl);

    // cov + fused argmin
    cov_mfma_kernel<<<dim3(2, NROWS / 64), 128, 0, stream>>>(
        zh, zl, cbh, cbl, ws + OFF_SQR, keys);

    decode_kernel<<<NROWS / 256, 256, 0, stream>>>(
        keys, wsi + OFF_CODES, out + OUT_CODES, wsi + OFF_HIST);

    prefix_kernel<<<1, 1024, 0, stream>>>(
        wsi + OFF_HIST, wsi + OFF_OFFS, ws + OFF_COUNTSF);

    fill_kernel<<<NROWS / 256, 256, 0, stream>>>(
        wsi + OFF_CODES, wsi + OFF_OFFS, wsi + OFF_CURSOR, wsi + OFF_LIST);

    upd_loss_kernel<<<NROWS / CHUNK, 256, 0, stream>>>(
        ws + OFF_Z, codebook, wsi + OFF_LIST, wsi + OFF_CODES,
        ws + OFF_UPD, ws + OFF_LOSS);

    recv_kernel<<<NROWS, 256, 0, stream>>>(
        ws + OFF_R, b_recv, wsi + OFF_CODES, out + OUT_X);

    ema_small_kernel<<<1, 1024, 0, stream>>>(
        ema_size, ws + OFF_COUNTSF, ws + OFF_LOSS, ws + OFF_SIZE, out);

    emav_kernel<<<KC, 256, 0, stream>>>(
        ema_vecs, ws + OFF_UPD, ws + OFF_SIZE, out);
}